// Round 6
// baseline (402.995 us; speedup 1.0000x reference)
//
#include <hip/hip_runtime.h>

// x:   (128, 128, 56, 56) f32     c = 2*k + i2
// w1:  (64, 3, 4) f32             w1[k, tap, j4]
// w2:  (2, 3, 32) f32             w2[i2, tap, j]
// t4:  (128, 8, 3136) f32 in ws   [l][(i2*4+j4)][m*56+o]
// out: (128, 128, 56, 56) f32     out[l][j*4+o4][m][n]
//
// Stage 1: t4[l,i2,m,o,j4] = sum_{k,tap} xroll[l,2k+i2, m+tap-1, o] * w1[k,tap,j4]
//   xroll row r -> src row (r==0?55:r-1) (roll +1 along H), zero outside 0<=r<56.
// Stage 2: out[l, 4j+o4, m, n] = sum_{i2,k} t4[l,i2,m,n+k-1,o4] * w2[i2,k,j]
//
// R5 lesson: stage1 issued 616 MB of loads (3-tap x 2-i2 re-reads) and sat at
// ~1 TB/s, latency/L3-bound. This version stages x in LDS once per block
// (235 MB total issued), with register-prefetch of the next channel batch
// (T14 async-stage split) so HBM latency hides under FMA compute.

__global__ __launch_bounds__(256) void stage1_kernel(
    const float* __restrict__ x, const float* __restrict__ w1,
    float* __restrict__ t4)
{
    // grid 512 = 128 l * 4 bands of 14 rows; XCD swizzle: 64 consecutive per XCD
    const int bid  = ((int)blockIdx.x & 7) * 64 + ((int)blockIdx.x >> 3);
    const int l    = bid >> 2;
    const int m0   = (bid & 3) * 14;
    const int tid  = threadIdx.x;

    // compute assignment: 196 chunks = 14 rows x 14 float4-cols
    const int row = tid / 14;            // valid when tid < 196
    const int nc  = tid - row * 14;
    const bool is_comp = (tid < 196);

    float vf[3];
#pragma unroll
    for (int t = 0; t < 3; ++t) {
        const int h = m0 + row + t - 1;  // global rolled-row index
        vf[t] = (h >= 0 && h < 56) ? 1.0f : 0.0f;
    }

    // x slab staged per 8-channel batch: xs[cc][lr][56], lr = local rolled row
    __shared__ float xs[8 * 16 * 56];    // 28,672 B

    // staging item -> global address (7 items per thread per batch)
    int   g_off[7];
    const float* xl = x + (size_t)l * (128 * 3136);
#pragma unroll
    for (int r = 0; r < 7; ++r) {
        const int it  = tid + r * 256;   // [0,1792)
        const int cc  = it / 224;
        const int rem = it - cc * 224;
        const int lr  = rem / 14;
        const int nc4 = rem - lr * 14;
        const int rr  = m0 - 1 + lr;                 // global rolled row
        const int src = (rr <= 0) ? 55 : (rr - 1);   // roll(+1); dummy when invalid
        g_off[r] = cc * 3136 + src * 56 + nc4 * 4;   // + c0*3136 added per batch
    }

    float acc[2][4][4] = {};             // [i2][j][o-sub]

    // prefetch batch 0 into registers
    float4 pre[7];
#pragma unroll
    for (int r = 0; r < 7; ++r)
        pre[r] = *reinterpret_cast<const float4*>(xl + g_off[r]);

    for (int b = 0; b < 16; ++b) {
        // write prefetched slab to LDS
#pragma unroll
        for (int r = 0; r < 7; ++r)
            *reinterpret_cast<float4*>(&xs[(tid + r * 256) * 4]) = pre[r];

        // issue next batch's loads (latency hides under compute below)
        if (b < 15) {
            const float* xb = xl + (size_t)(b + 1) * 8 * 3136;
#pragma unroll
            for (int r = 0; r < 7; ++r)
                pre[r] = *reinterpret_cast<const float4*>(xb + g_off[r]);
        }
        __syncthreads();                 // slab visible

        if (is_comp) {
#pragma unroll
            for (int cc = 0; cc < 8; ++cc) {
                const int c  = b * 8 + cc;
                const int k  = c >> 1;
                const int i2 = c & 1;
                float w[3][4];
#pragma unroll
                for (int t = 0; t < 3; ++t)
#pragma unroll
                    for (int j = 0; j < 4; ++j)
                        w[t][j] = w1[(k * 3 + t) * 4 + j] * vf[t];  // s_load * vf
#pragma unroll
                for (int t = 0; t < 3; ++t) {
                    const float4 xv = *reinterpret_cast<const float4*>(
                        &xs[((cc * 16 + row + t) * 56) + nc * 4]);
#pragma unroll
                    for (int j = 0; j < 4; ++j) {
                        acc[i2][j][0] = fmaf(xv.x, w[t][j], acc[i2][j][0]);
                        acc[i2][j][1] = fmaf(xv.y, w[t][j], acc[i2][j][1]);
                        acc[i2][j][2] = fmaf(xv.z, w[t][j], acc[i2][j][2]);
                        acc[i2][j][3] = fmaf(xv.w, w[t][j], acc[i2][j][3]);
                    }
                }
            }
        }
        __syncthreads();                 // slab free for overwrite
    }

    if (is_comp) {
        float* tp = t4 + (size_t)l * (8 * 3136) + (m0 + row) * 56 + nc * 4;
#pragma unroll
        for (int i2 = 0; i2 < 2; ++i2)
#pragma unroll
            for (int j = 0; j < 4; ++j) {
                *reinterpret_cast<float4*>(tp + (size_t)(i2 * 4 + j) * 3136) =
                    make_float4(acc[i2][j][0], acc[i2][j][1],
                                acc[i2][j][2], acc[i2][j][3]);
            }
    }
}

__global__ __launch_bounds__(256) void stage2_kernel(
    const float* __restrict__ t4, const float* __restrict__ w2,
    float* __restrict__ out)
{
    // block = (l, m-pair): 3584 blocks, 256 threads
    const int bid = ((int)blockIdx.x & 7) * 448 + ((int)blockIdx.x >> 3);
    const int l   = bid / 28;
    const int m0  = (bid - l * 28) * 2;
    const int tid = threadIdx.x;

    // t4 tile padded: index nn in [-1,56] -> col nn+4 in [3,60]; zeros at 3,60.
    // Row width 64 floats keeps float4 stage-writes 16B-aligned at col 4+4*nc.
    __shared__ float tl[8 * 2 * 64];     // 4 KB
    __shared__ float w2l[192];

    if (tid < 192) w2l[tid] = w2[tid];
    if (tid < 32) {                      // zero pads: 8 outs x 2 rows x 2 cols
        const int o  = tid >> 2;
        const int rw = (tid >> 1) & 1;
        const int cl = (tid & 1) ? 60 : 3;
        tl[(o * 2 + rw) * 64 + cl] = 0.0f;
    }
    if (tid < 224) {                     // stage 8 outs x 2 rows x 14 float4
        const int o   = tid / 28;
        const int rem = tid - o * 28;
        const int rw  = rem / 14;
        const int nc  = rem - rw * 14;
        const float4 v = *reinterpret_cast<const float4*>(
            t4 + ((size_t)l * 8 + o) * 3136 + (m0 + rw) * 56 + nc * 4);
        *reinterpret_cast<float4*>(&tl[(o * 2 + rw) * 64 + 4 + nc * 4]) = v;
    }
    __syncthreads();

    const int o4 = tid >> 6;             // wave id
    const int ln = tid & 63;

    float* ob = out + ((size_t)l * 128 + o4) * 3136 + m0 * 56;

#pragma unroll 2
    for (int r = 0; r < 14; ++r) {       // 896 tasks per o4 = 14 rounds x 64 lanes
        const int task = r * 64 + ln;    // (j, row, nc)
        const int j    = task / 28;
        const int rem  = task - j * 28;
        const int rw   = rem / 14;
        const int nc   = rem - rw * 14;

        float tv[2][6];                  // nn = nc*4 - 1 + d
#pragma unroll
        for (int i = 0; i < 2; ++i) {
            const float* tb = &tl[((i * 4 + o4) * 2 + rw) * 64 + 3 + nc * 4];
#pragma unroll
            for (int d = 0; d < 6; ++d) tv[i][d] = tb[d];
        }

        float4 s = make_float4(0.f, 0.f, 0.f, 0.f);
#pragma unroll
        for (int i = 0; i < 2; ++i)
#pragma unroll
            for (int k = 0; k < 3; ++k) {
                const float wv = w2l[(i * 3 + k) * 32 + j];
                s.x = fmaf(tv[i][k + 0], wv, s.x);
                s.y = fmaf(tv[i][k + 1], wv, s.y);
                s.z = fmaf(tv[i][k + 2], wv, s.z);
                s.w = fmaf(tv[i][k + 3], wv, s.w);
            }
        // c = 4j + o4
        *reinterpret_cast<float4*>(
            ob + (size_t)(4 * j) * 3136 + rw * 56 + nc * 4) = s;
    }
}

extern "C" void kernel_launch(void* const* d_in, const int* in_sizes, int n_in,
                              void* d_out, int out_size, void* d_ws, size_t ws_size,
                              hipStream_t stream)
{
    const float* x  = (const float*)d_in[0];
    const float* w1 = (const float*)d_in[1];
    const float* w2 = (const float*)d_in[2];
    float* out = (float*)d_out;
    float* t4  = (float*)d_ws;           // 128*8*3136*4 = 12.8 MB

    stage1_kernel<<<dim3(512), dim3(256), 0, stream>>>(x, w1, t4);
    stage2_kernel<<<dim3(3584), dim3(256), 0, stream>>>(t4, w2, out);
}